// Round 12
// baseline (1632.959 us; speedup 1.0000x reference)
//
#include <hip/hip_runtime.h>
#include <hip/hip_bf16.h>

typedef __attribute__((ext_vector_type(8))) __bf16 bf16x8;
typedef __attribute__((ext_vector_type(8))) short short8;
typedef __attribute__((ext_vector_type(4))) float floatx4;
typedef __attribute__((ext_vector_type(2))) float floatx2;
using u16 = unsigned short;

#define GLOBAL_AS __attribute__((address_space(1)))
#define LDS_AS    __attribute__((address_space(3)))

__device__ __forceinline__ float b2f(u16 u) {
    union { unsigned int i; float f; } v; v.i = ((unsigned int)u) << 16; return v.f;
}
__device__ __forceinline__ u16 f2b(float f) {
    __hip_bfloat16 h = __float2bfloat16(f);
    return __builtin_bit_cast(u16, h);
}
__device__ __forceinline__ float ldf(const void* p, long i, bool isf32) {
    return isf32 ? ((const float*)p)[i] : b2f(((const u16*)p)[i]);
}
// async global->LDS, 16B per lane; lds base must be wave-uniform
__device__ __forceinline__ void gload_lds16(const void* g, void* l) {
    __builtin_amdgcn_global_load_lds((const GLOBAL_AS unsigned int*)g,
                                     (LDS_AS unsigned int*)l, 16, 0, 0);
}
// sum over 8 consecutive lanes, result in all 8 lanes (VALU DPP, no LDS)
__device__ __forceinline__ float red8(float x) {
    int xi, yi;
    xi = __builtin_bit_cast(int, x);
    yi = __builtin_amdgcn_update_dpp(xi, xi, 0xB1, 0xF, 0xF, false);   // quad_perm [1,0,3,2]
    x += __builtin_bit_cast(float, yi);
    xi = __builtin_bit_cast(int, x);
    yi = __builtin_amdgcn_update_dpp(xi, xi, 0x4E, 0xF, 0xF, false);   // quad_perm [2,3,0,1]
    x += __builtin_bit_cast(float, yi);
    xi = __builtin_bit_cast(int, x);
    yi = __builtin_amdgcn_update_dpp(xi, xi, 0x141, 0xF, 0xF, false);  // row_half_mirror
    x += __builtin_bit_cast(float, yi);
    return x;
}
// packed 2xf32 fma -> v_pk_fma_f32 on CDNA2+ (graceful: 2 scalar fma if not)
__device__ __forceinline__ floatx2 fma2(floatx2 a, floatx2 b, floatx2 c) {
    return __builtin_elementwise_fma(a, b, c);
}
__device__ __forceinline__ void unpack2(int d, float& lo, float& hi) {
    lo = __builtin_bit_cast(float, (int)((unsigned)d << 16));
    hi = __builtin_bit_cast(float, d & 0xffff0000);
}
__device__ __forceinline__ void unpack8(int4 d, float* f) {
    unpack2(d.x, f[0], f[1]); unpack2(d.y, f[2], f[3]);
    unpack2(d.z, f[4], f[5]); unpack2(d.w, f[6], f[7]);
}

// ---------------------------------------------------------------------------
// dtype detector (1 = inputs are f32)
// ---------------------------------------------------------------------------
__global__ void detect_dtype(const unsigned int* __restrict__ x, int* __restrict__ flag) {
    const int lane = threadIdx.x;
    int sane = 0;
    for (int i = lane; i < 256; i += 64) {
        const unsigned e = (x[i] >> 23) & 0xFF;
        sane += (e >= 100 && e <= 140) ? 1 : 0;
    }
#pragma unroll
    for (int m = 1; m < 64; m <<= 1) sane += __shfl_xor(sane, m, 64);
    if (lane == 0) *flag = (sane >= 128) ? 1 : 0;
}

// ---------------------------------------------------------------------------
// convert external tensor (f32 or bf16 per flag) -> bf16 buffer. n % 2048 == 0
// ---------------------------------------------------------------------------
__global__ __launch_bounds__(256) void cvt_bf16(
    const void* __restrict__ in, u16* __restrict__ out, long n, const int* __restrict__ flag) {
    const bool f32 = (*flag != 0);
    const long i = ((long)blockIdx.x * 256 + threadIdx.x) * 8;
    if (i >= n) return;
    if (f32) {
        const float* p = (const float*)in + i;
        floatx4 a = *(const floatx4*)p, b = *(const floatx4*)(p + 4);
        short8 o;
        o[0] = (short)f2b(a[0]); o[1] = (short)f2b(a[1]);
        o[2] = (short)f2b(a[2]); o[3] = (short)f2b(a[3]);
        o[4] = (short)f2b(b[0]); o[5] = (short)f2b(b[1]);
        o[6] = (short)f2b(b[2]); o[7] = (short)f2b(b[3]);
        *(short8*)(out + i) = o;
    } else {
        *(int4*)(out + i) = *(const int4*)((const u16*)in + i);
    }
}

// ---------------------------------------------------------------------------
// m97-class GEMM: C[M,N] = A[M,K] * B[N,K]^T, A/B bf16 row-major.
// 128x128 tile, BK=32, global_load_lds(16B), 4 waves x (4x4) 16x16x32 MFMA.
// cmode: 1 = f32 C, 3 = bf16 C, 2 = per-flag (f32 if flag else bf16)
// cmode 4 = fused QKV epilogue: C points at qpreb; n<2048 -> qpreb[m][n],
//           n<4096 -> kpreb[m][n-2048] (+4096*2048 elems), else
//           vpreb[m][n-4096] (+2*4096*2048 elems, stride 4096).
//           Region is block-uniform (boundaries are multiples of 128).
// ---------------------------------------------------------------------------
__global__ __launch_bounds__(256) void gemm_bt128(
    const u16* __restrict__ A, const u16* __restrict__ B, void* __restrict__ C,
    int M, int N, int K, int cmode, const int* __restrict__ flag) {
    const bool c32 = (cmode == 1) || (cmode == 2 && *flag != 0);
    const bool qkv = (cmode == 4);
    __shared__ __align__(16) u16 As[128 * 32];
    __shared__ __align__(16) u16 Bs[128 * 32];
    const int tid = threadIdx.x, lane = tid & 63, wave = tid >> 6;
    const int bm = blockIdx.y * 128, bn = blockIdx.x * 128;
    const int wm = (wave >> 1) * 64, wn = (wave & 1) * 64;
    const int fr = lane & 15, fq = lane >> 4;
    floatx4 acc[4][4] = {};

    const int srow = tid >> 2, scol = (tid & 3) * 8;       // 64 rows per call
    const long abase = (long)(bm + srow) * K + scol;
    const long bbase = (long)(bn + srow) * K + scol;
    char* lA = (char*)As + (tid & ~63) * 16;
    char* lB = (char*)Bs + (tid & ~63) * 16;

    for (int k0 = 0; k0 < K; k0 += 32) {
        __syncthreads();
        gload_lds16(A + abase + k0, lA);
        gload_lds16(A + abase + (long)64 * K + k0, lA + 4096);
        gload_lds16(B + bbase + k0, lB);
        gload_lds16(B + bbase + (long)64 * K + k0, lB + 4096);
        __syncthreads();
        bf16x8 af[4], bf[4];
#pragma unroll
        for (int i = 0; i < 4; i++) {
            af[i] = __builtin_bit_cast(bf16x8, *(const short8*)&As[(wm + i * 16 + fr) * 32 + fq * 8]);
            bf[i] = __builtin_bit_cast(bf16x8, *(const short8*)&Bs[(wn + i * 16 + fr) * 32 + fq * 8]);
        }
#pragma unroll
        for (int mi = 0; mi < 4; mi++)
#pragma unroll
            for (int ni = 0; ni < 4; ni++)
                acc[mi][ni] = __builtin_amdgcn_mfma_f32_16x16x32_bf16(
                    af[mi], bf[ni], acc[mi][ni], 0, 0, 0);
    }
#pragma unroll
    for (int mi = 0; mi < 4; mi++)
#pragma unroll
        for (int ni = 0; ni < 4; ni++)
#pragma unroll
            for (int r = 0; r < 4; r++) {
                const int m = bm + wm + mi * 16 + fq * 4 + r;
                const int n = bn + wn + ni * 16 + fr;
                const float val = acc[mi][ni][r];
                if (qkv) {
                    u16* base = (u16*)C;
                    long off;
                    if (n < 2048)      off = (long)m * 2048 + n;
                    else if (n < 4096) off = 8388608L + (long)m * 2048 + (n - 2048);
                    else               off = 16777216L + (long)m * 4096 + (n - 4096);
                    base[off] = f2b(val);
                } else {
                    const long ci = (long)m * N + n;
                    if (c32) ((float*)C)[ci] = val;
                    else ((u16*)C)[ci] = f2b(val);
                }
            }
}

// ---------------------------------------------------------------------------
// alpha/beta via MFMA: [4096,2048]x[32,2048]^T, sigmoid fused, transposed
// write to alphaT/betaT [b*16+h][T]. 64 blocks x (64m x 32n), BK=64.
// ---------------------------------------------------------------------------
__global__ __launch_bounds__(256) void ab_gemm(
    const u16* __restrict__ xb, const u16* __restrict__ wab,
    float* __restrict__ alphaT, float* __restrict__ betaT) {
    __shared__ __align__(16) u16 As[64 * 64];  // 8 KB
    __shared__ __align__(16) u16 Bs[32 * 64];  // 4 KB
    const int tid = threadIdx.x, lane = tid & 63, wave = tid >> 6;
    const int bm = blockIdx.x * 64;
    const int fr = lane & 15, fq = lane >> 4;
    floatx4 acc[2] = {};

    const int srow = tid >> 3, scol = (tid & 7) * 8;  // 32 rows x 64 cols per call
    char* lA = (char*)As + (tid & ~63) * 16;
    char* lB = (char*)Bs + (tid & ~63) * 16;

    for (int k0 = 0; k0 < 2048; k0 += 64) {
        __syncthreads();
        gload_lds16(xb + (long)(bm + srow) * 2048 + k0 + scol, lA);
        // rows 32..63 start at element 32*64=2048 -> byte offset 4096
        gload_lds16(xb + (long)(bm + 32 + srow) * 2048 + k0 + scol, lA + 4096);
        gload_lds16(wab + (long)srow * 2048 + k0 + scol, lB);
        __syncthreads();
#pragma unroll
        for (int ks = 0; ks < 2; ks++) {
            bf16x8 af = __builtin_bit_cast(bf16x8,
                *(const short8*)&As[(wave * 16 + fr) * 64 + ks * 32 + fq * 8]);
#pragma unroll
            for (int nt = 0; nt < 2; nt++) {
                bf16x8 bf = __builtin_bit_cast(bf16x8,
                    *(const short8*)&Bs[(nt * 16 + fr) * 64 + ks * 32 + fq * 8]);
                acc[nt] = __builtin_amdgcn_mfma_f32_16x16x32_bf16(af, bf, acc[nt], 0, 0, 0);
            }
        }
    }
#pragma unroll
    for (int nt = 0; nt < 2; nt++)
#pragma unroll
        for (int r = 0; r < 4; r++) {
            const int m = bm + wave * 16 + fq * 4 + r;
            const int n = nt * 16 + fr;
            const int b = m >> 11, t = m & 2047;
            const float s = 1.f / (1.f + __expf(-acc[nt][r]));
            if (n < 16) alphaT[((long)b * 16 + n) * 2048 + t] = s;
            else betaT[((long)b * 16 + (n - 16)) * 2048 + t] = s;
        }
}

// ---------------------------------------------------------------------------
// causal depthwise conv K=4 + SiLU + per-head(128) L2 norm. pre is bf16.
// ---------------------------------------------------------------------------
__global__ __launch_bounds__(256) void conv_silu_norm(
    const u16* __restrict__ pre, const void* __restrict__ cw,
    const void* __restrict__ cb, u16* __restrict__ out, const int* __restrict__ flag) {
    const bool f32 = (*flag != 0);
    const int bt = blockIdx.x;
    const int t = bt & 2047;
    const int tid = threadIdx.x;
    const int c0 = tid * 8;
    float y[8];
    float ss = 0.f;
#pragma unroll
    for (int j = 0; j < 8; j++) {
        const int c = c0 + j;
        float acc = ldf(cb, c, f32);
#pragma unroll
        for (int i = 0; i < 4; i++) {
            if (t - 3 + i >= 0)
                acc += ldf(cw, c * 4 + i, f32) * b2f(pre[(long)(bt - 3 + i) * 2048 + c]);
        }
        const float s = acc / (1.f + __expf(-acc));
        y[j] = s;
        ss += s * s;
    }
#pragma unroll
    for (int m = 1; m < 16; m <<= 1) ss += __shfl_xor(ss, m, 64);
    const float inv = rsqrtf(ss + 1e-12f);
#pragma unroll
    for (int j = 0; j < 8; j++) out[(long)bt * 2048 + c0 + j] = f2b(y[j] * inv);
}

__global__ __launch_bounds__(256) void conv_silu_v(
    const u16* __restrict__ pre, const void* __restrict__ cw,
    const void* __restrict__ cb, u16* __restrict__ out, const int* __restrict__ flag) {
    const bool f32 = (*flag != 0);
    const int bt = blockIdx.x;
    const int t = bt & 2047;
    const int tid = threadIdx.x;
    const int c0 = tid * 16;
#pragma unroll
    for (int j = 0; j < 16; j++) {
        const int c = c0 + j;
        float acc = ldf(cb, c, f32);
#pragma unroll
        for (int i = 0; i < 4; i++) {
            if (t - 3 + i >= 0)
                acc += ldf(cw, c * 4 + i, f32) * b2f(pre[(long)(bt - 3 + i) * 4096 + c]);
        }
        out[(long)bt * 4096 + c] = f2b(acc / (1.f + __expf(-acc)));
    }
}

// ---------------------------------------------------------------------------
// Gated delta-rule recurrence, barrier-free steps (DPP k-reduction).
// 256 blocks = (b,h,vb); lane = vq*8+kg owns S[kg*16+j][v]; red8 k-reduce.
// R11 (R10 post-mortem: busy 272 cyc/step is near the FLOP floor; idle 276
// attributed to the serial chain r->red8->err->cc->S-update->o-dot->red8):
//  - dependency break: o = q.S_new = a*(q.S_old) + cc*(q.k). The three dot
//    products (S.k, S.q, k.q) depend only on step inputs -> computed in
//    parallel; critical path drops to one red8 + err + cc + fma (~60 cyc
//    vs ~110). Costs +8 pk-fma + 1 red8 per step (+~28 busy cyc).
//  - everything else identical to R10 (f32 LDS staging, T14 async split,
//    fully-unrolled tt loop, packed float2 math).
// ---------------------------------------------------------------------------
__global__ __launch_bounds__(256) void recurrence_kernel(
    const u16* __restrict__ qn, const u16* __restrict__ kn,
    const u16* __restrict__ vn, const float* __restrict__ alphaT,
    const float* __restrict__ betaT, const void* __restrict__ state_in,
    u16* __restrict__ outs, void* __restrict__ d_out, const int* __restrict__ flag) {
    const bool f32 = (*flag != 0);
    const int blk = blockIdx.x;
    const int vb = blk & 7, h = (blk >> 3) & 15, b = blk >> 7;
    const int tid = threadIdx.x, lane = tid & 63, wave = tid >> 6;
    const int kg = lane & 7, vq = lane >> 3;
    const int vloc = wave * 8 + vq;          // 0..31
    const int vglob = vb * 32 + vloc;

    // S2[p] = {S[2p], S[2p+1]}, state rows kg*16 + 2p, 2p+1
    floatx2 S2[8];
    const long stbase = ((long)(b * 16 + h) * 128 + kg * 16) * 256 + vglob;
#pragma unroll
    for (int p = 0; p < 8; p++) {
        S2[p][0] = ldf(state_in, stbase + (long)(2 * p) * 256, f32);
        S2[p][1] = ldf(state_in, stbase + (long)(2 * p + 1) * 256, f32);
    }

    // double-buffered f32 LDS (36 KB total)
    __shared__ __align__(16) float kf[2][16 * 128];
    __shared__ __align__(16) float qf[2][16 * 128];
    __shared__ __align__(16) float vf[2][16 * 32];

    // staging assignment: 16 rows x (16 threads x 8 cols) for k/q,
    // 16 rows x (16 threads x 2 cols) for v
    const int srow = tid >> 4, sc8 = (tid & 15) * 8, vc2 = (tid & 15) * 2;
    const long gkq0 = ((long)b * 2048 + srow) * 2048 + h * 128 + sc8;
    const long gv0  = ((long)b * 2048 + srow) * 4096 + h * 256 + vb * 32 + vc2;
    const long abase = (long)(b * 16 + h) * 2048;

    int4 gk, gq;
    unsigned int gv;
    float ga, gb;

    auto stage_write = [&](int buf) {
        const int kgg = sc8 >> 4, i0 = (sc8 >> 2) & 3;  // i0 in {0,2}
        float fk[8], fq_[8];
        unpack8(gk, fk);
        unpack8(gq, fq_);
        const int base = srow * 128 + kgg * 4;
        *(floatx4*)&kf[buf][base + i0 * 32]       = floatx4{fk[0], fk[1], fk[2], fk[3]};
        *(floatx4*)&kf[buf][base + (i0 + 1) * 32] = floatx4{fk[4], fk[5], fk[6], fk[7]};
        *(floatx4*)&qf[buf][base + i0 * 32]       = floatx4{fq_[0], fq_[1], fq_[2], fq_[3]};
        *(floatx4*)&qf[buf][base + (i0 + 1) * 32] = floatx4{fq_[4], fq_[5], fq_[6], fq_[7]};
        vf[buf][srow * 32 + vc2]     = b2f((u16)(gv & 0xffffu));
        vf[buf][srow * 32 + vc2 + 1] = b2f((u16)(gv >> 16));
    };

    // prologue: load + stage chunk 0
    gk = *(const int4*)(kn + gkq0);
    gq = *(const int4*)(qn + gkq0);
    gv = *(const unsigned int*)(vn + gv0);
    ga = alphaT[abase + (lane & 15)];
    gb = betaT[abase + (lane & 15)];
    stage_write(0);
    __syncthreads();

    for (int c = 0; c < 128; ++c) {
        const int cur = c & 1;
        const float aw = ga, bw = gb;  // capture current chunk's alpha/beta
        if (c + 1 < 128) {
            // T14: issue next chunk's global loads (consumed after compute)
            const long off = (long)(c + 1) * 16 * 2048;
            gk = *(const int4*)(kn + gkq0 + off);
            gq = *(const int4*)(qn + gkq0 + off);
            gv = *(const unsigned int*)(vn + gv0 + (long)(c + 1) * 16 * 4096);
            ga = alphaT[abase + (c + 1) * 16 + (lane & 15)];
            gb = betaT[abase + (c + 1) * 16 + (lane & 15)];
        }

        const float* kfp = kf[cur];
        const float* qfp = qf[cur];
        const float* vfp = vf[cur];
        const long obase = ((long)b * 2048 + c * 16) * 4096 + h * 256 + vglob;

#pragma unroll
        for (int tt = 0; tt < 16; ++tt) {
            // fragments: value kg*16 + i*4 + j at word tt*128 + i*32 + kg*4 + j
            floatx2 k2[8], q2[8];
#pragma unroll
            for (int i = 0; i < 4; i++) {
                const floatx4 k4 = *(const floatx4*)&kfp[tt * 128 + i * 32 + kg * 4];
                const floatx4 q4 = *(const floatx4*)&qfp[tt * 128 + i * 32 + kg * 4];
                k2[i * 2]     = __builtin_shufflevector(k4, k4, 0, 1);
                k2[i * 2 + 1] = __builtin_shufflevector(k4, k4, 2, 3);
                q2[i * 2]     = __builtin_shufflevector(q4, q4, 0, 1);
                q2[i * 2 + 1] = __builtin_shufflevector(q4, q4, 2, 3);
            }
            const float vcur = vfp[tt * 32 + vloc];
            const float a = __builtin_bit_cast(float,
                __builtin_amdgcn_readlane(__builtin_bit_cast(int, aw), tt));
            const float bb = __builtin_bit_cast(float,
                __builtin_amdgcn_readlane(__builtin_bit_cast(int, bw), tt));

            // three parallel dot products over S_old / inputs (no chain dep)
            floatx2 rA = {0.f, 0.f}, rB = {0.f, 0.f};   // S_old . k
            floatx2 sA = {0.f, 0.f}, sB = {0.f, 0.f};   // S_old . q
            floatx2 tA = {0.f, 0.f}, tB = {0.f, 0.f};   // k . q
#pragma unroll
            for (int p = 0; p < 4; p++) {
                rA = fma2(S2[p], k2[p], rA);
                rB = fma2(S2[4 + p], k2[4 + p], rB);
                sA = fma2(S2[p], q2[p], sA);
                sB = fma2(S2[4 + p], q2[4 + p], sB);
                tA = fma2(k2[p], q2[p], tA);
                tB = fma2(k2[4 + p], q2[4 + p], tB);
            }
            const floatx2 rS = rA + rB, sS = sA + sB, tS = tA + tB;
            const float r   = red8(rS[0] + rS[1]);
            const float rqs = red8(sS[0] + sS[1]);
            const float rqk = red8(tS[0] + tS[1]);
            const float err = fmaf(-a, r, vcur);
            const float cc  = bb * err;
            // o = q . S_new = a*(q.S_old) + cc*(q.k)
            const float o = fmaf(cc, rqk, a * rqs);
            const floatx2 a2 = {a, a}, cc2 = {cc, cc};
#pragma unroll
            for (int p = 0; p < 4; p++) {
                S2[p]     = fma2(cc2, k2[p],     a2 * S2[p]);
                S2[4 + p] = fma2(cc2, k2[4 + p], a2 * S2[4 + p]);
            }
            if (kg == 0)
                outs[obase + (long)tt * 4096] = f2b(o);
        }

        if (c + 1 < 128) stage_write(cur ^ 1);  // compiler inserts vmcnt wait here
        __syncthreads();
    }

    // final state -> d_out at element offset B*T*H = 8388608
#pragma unroll
    for (int p = 0; p < 8; p++) {
#pragma unroll
        for (int e = 0; e < 2; e++) {
            const long idx = 8388608L + stbase + (long)(2 * p + e) * 256;
            if (f32) ((float*)d_out)[idx] = S2[p][e];
            else ((u16*)d_out)[idx] = f2b(S2[p][e]);
        }
    }
}

// ---------------------------------------------------------------------------
extern "C" void kernel_launch(void* const* d_in, const int* in_sizes, int n_in,
                              void* d_out, int out_size, void* d_ws, size_t ws_size,
                              hipStream_t stream) {
    const void* x   = d_in[0];
    const void* st0 = d_in[1];
    const void* Wq  = d_in[2];
    const void* Wk  = d_in[3];
    const void* Wv  = d_in[4];
    const void* Wo  = d_in[5];
    const void* Wa  = d_in[6];
    const void* Wb  = d_in[7];
    const void* qcW = d_in[8];
    const void* qcB = d_in[9];
    const void* kcW = d_in[10];
    const void* kcB = d_in[11];
    const void* vcW = d_in[12];
    const void* vcB = d_in[13];

    const int M = 4096;  // B*T
    const long MB = 1024L * 1024L;
    char* w = (char*)d_ws;
    int*   flag   = (int*)w;                       // @0, 1KB pad
    float* alphaT = (float*)(w + 1024);            // 256 KB
    float* betaT  = (float*)(w + 1024 + 262144);   // 256 KB
    u16*   wab    = (u16*)(w + 1024 + 524288);     // 128 KB (Wa||Wb bf16)
    u16* xb    = (u16*)(w + 1 * MB);               // 16 MB  (reused for Wo later)
    u16* wqb   = (u16*)(w + 17 * MB);              // 8 MB   (wqb/wkb/wvb contiguous:
    u16* wkb   = (u16*)(w + 25 * MB);              // 8 MB    fused [8192,2048] B)
    u16* wvb   = (u16*)(w + 33 * MB);              // 16 MB
    u16* qpreb = (u16*)(w + 49 * MB);              // 16 MB  (qpreb/kpreb/vpreb
    u16* kpreb = (u16*)(w + 65 * MB);              // 16 MB   contiguous: fused C)
    u16* vpreb = (u16*)(w + 81 * MB);              // 32 MB
    u16* qn    = (u16*)(w + 113 * MB);             // 16 MB
    u16* kn    = (u16*)(w + 129 * MB);             // 16 MB
    u16* vn    = (u16*)(w + 145 * MB);             // 32 MB (ends 177 MB)
    u16* wob   = xb;                               // alias: x dead after proj GEMMs + ab_gemm
    u16* outs  = qpreb;                            // alias: 32 MB (qpreb+kpreb)

    dim3 blk(256);
    detect_dtype<<<dim3(1), dim3(64), 0, stream>>>((const unsigned int*)x, flag);

    cvt_bf16<<<dim3(4096), blk, 0, stream>>>(x,  xb,  8388608L, flag);
    cvt_bf16<<<dim3(2048), blk, 0, stream>>>(Wq, wqb, 4194304L, flag);
    cvt_bf16<<<dim3(2048), blk, 0, stream>>>(Wk, wkb, 4194304L, flag);
    cvt_bf16<<<dim3(4096), blk, 0, stream>>>(Wv, wvb, 8388608L, flag);
    cvt_bf16<<<dim3(16),   blk, 0, stream>>>(Wa, wab, 32768L, flag);
    cvt_bf16<<<dim3(16),   blk, 0, stream>>>(Wb, wab + 32768, 32768L, flag);

    // fused QKV projection: one [4096,8192,2048] GEMM (cmode 4 splits C into
    // qpreb/kpreb/vpreb). Replaces 3 launches; 2048 blocks.
    gemm_bt128<<<dim3(8192 / 128, M / 128), blk, 0, stream>>>(xb, wqb, qpreb, M, 8192, 2048, 4, flag);
    ab_gemm<<<dim3(64), blk, 0, stream>>>(xb, wab, alphaT, betaT);

    cvt_bf16<<<dim3(4096), blk, 0, stream>>>(Wo, wob, 8388608L, flag);  // after all xb readers

    conv_silu_norm<<<dim3(M), blk, 0, stream>>>(qpreb, qcW, qcB, qn, flag);
    conv_silu_norm<<<dim3(M), blk, 0, stream>>>(kpreb, kcW, kcB, kn, flag);
    conv_silu_v<<<dim3(M), blk, 0, stream>>>(vpreb, vcW, vcB, vn, flag);

    recurrence_kernel<<<dim3(256), blk, 0, stream>>>(qn, kn, vn, alphaT, betaT, st0,
                                                     outs, d_out, flag);

    gemm_bt128<<<dim3(2048 / 128, M / 128), blk, 0, stream>>>(outs, wob, d_out, M, 2048, 4096, 2, flag);
}

// Round 21
// 1571.974 us; speedup vs baseline: 1.0388x; 1.0388x over previous
//
#include <hip/hip_runtime.h>
#include <hip/hip_bf16.h>

typedef __attribute__((ext_vector_type(8))) __bf16 bf16x8;
typedef __attribute__((ext_vector_type(8))) short short8;
typedef __attribute__((ext_vector_type(4))) float floatx4;
typedef __attribute__((ext_vector_type(2))) float floatx2;
using u16 = unsigned short;

#define GLOBAL_AS __attribute__((address_space(1)))
#define LDS_AS    __attribute__((address_space(3)))

__device__ __forceinline__ float b2f(u16 u) {
    union { unsigned int i; float f; } v; v.i = ((unsigned int)u) << 16; return v.f;
}
__device__ __forceinline__ u16 f2b(float f) {
    __hip_bfloat16 h = __float2bfloat16(f);
    return __builtin_bit_cast(u16, h);
}
__device__ __forceinline__ float ldf(const void* p, long i, bool isf32) {
    return isf32 ? ((const float*)p)[i] : b2f(((const u16*)p)[i]);
}
// async global->LDS, 16B per lane; lds base must be wave-uniform
__device__ __forceinline__ void gload_lds16(const void* g, void* l) {
    __builtin_amdgcn_global_load_lds((const GLOBAL_AS unsigned int*)g,
                                     (LDS_AS unsigned int*)l, 16, 0, 0);
}
// sum over 8 consecutive lanes, result in all 8 lanes (VALU DPP, no LDS)
__device__ __forceinline__ float red8(float x) {
    int xi, yi;
    xi = __builtin_bit_cast(int, x);
    yi = __builtin_amdgcn_update_dpp(xi, xi, 0xB1, 0xF, 0xF, false);   // quad_perm [1,0,3,2]
    x += __builtin_bit_cast(float, yi);
    xi = __builtin_bit_cast(int, x);
    yi = __builtin_amdgcn_update_dpp(xi, xi, 0x4E, 0xF, 0xF, false);   // quad_perm [2,3,0,1]
    x += __builtin_bit_cast(float, yi);
    xi = __builtin_bit_cast(int, x);
    yi = __builtin_amdgcn_update_dpp(xi, xi, 0x141, 0xF, 0xF, false);  // row_half_mirror
    x += __builtin_bit_cast(float, yi);
    return x;
}
// packed 2xf32 fma -> v_pk_fma_f32 on CDNA2+ (graceful: 2 scalar fma if not)
__device__ __forceinline__ floatx2 fma2(floatx2 a, floatx2 b, floatx2 c) {
    return __builtin_elementwise_fma(a, b, c);
}
__device__ __forceinline__ void unpack2(int d, float& lo, float& hi) {
    lo = __builtin_bit_cast(float, (int)((unsigned)d << 16));
    hi = __builtin_bit_cast(float, d & 0xffff0000);
}
__device__ __forceinline__ void unpack8(int4 d, float* f) {
    unpack2(d.x, f[0], f[1]); unpack2(d.y, f[2], f[3]);
    unpack2(d.z, f[4], f[5]); unpack2(d.w, f[6], f[7]);
}

// ---------------------------------------------------------------------------
// dtype detector (1 = inputs are f32)
// ---------------------------------------------------------------------------
__global__ void detect_dtype(const unsigned int* __restrict__ x, int* __restrict__ flag) {
    const int lane = threadIdx.x;
    int sane = 0;
    for (int i = lane; i < 256; i += 64) {
        const unsigned e = (x[i] >> 23) & 0xFF;
        sane += (e >= 100 && e <= 140) ? 1 : 0;
    }
#pragma unroll
    for (int m = 1; m < 64; m <<= 1) sane += __shfl_xor(sane, m, 64);
    if (lane == 0) *flag = (sane >= 128) ? 1 : 0;
}

// ---------------------------------------------------------------------------
// convert external tensor (f32 or bf16 per flag) -> bf16 buffer. n % 2048 == 0
// ---------------------------------------------------------------------------
__global__ __launch_bounds__(256) void cvt_bf16(
    const void* __restrict__ in, u16* __restrict__ out, long n, const int* __restrict__ flag) {
    const bool f32 = (*flag != 0);
    const long i = ((long)blockIdx.x * 256 + threadIdx.x) * 8;
    if (i >= n) return;
    if (f32) {
        const float* p = (const float*)in + i;
        floatx4 a = *(const floatx4*)p, b = *(const floatx4*)(p + 4);
        short8 o;
        o[0] = (short)f2b(a[0]); o[1] = (short)f2b(a[1]);
        o[2] = (short)f2b(a[2]); o[3] = (short)f2b(a[3]);
        o[4] = (short)f2b(b[0]); o[5] = (short)f2b(b[1]);
        o[6] = (short)f2b(b[2]); o[7] = (short)f2b(b[3]);
        *(short8*)(out + i) = o;
    } else {
        *(int4*)(out + i) = *(const int4*)((const u16*)in + i);
    }
}

// ---------------------------------------------------------------------------
// m97-class GEMM: C[M,N] = A[M,K] * B[N,K]^T, A/B bf16 row-major.
// 128x128 tile, BK=32, global_load_lds(16B), 4 waves x (4x4) 16x16x32 MFMA.
// cmode: 1 = f32 C, 3 = bf16 C, 2 = per-flag (f32 if flag else bf16)
// cmode 4 = fused QKV epilogue: C points at qpreb; n<2048 -> qpreb[m][n],
//           n<4096 -> kpreb[m][n-2048] (+4096*2048 elems), else
//           vpreb[m][n-4096] (+2*4096*2048 elems, stride 4096).
//           Region is block-uniform (boundaries are multiples of 128).
// ---------------------------------------------------------------------------
__global__ __launch_bounds__(256) void gemm_bt128(
    const u16* __restrict__ A, const u16* __restrict__ B, void* __restrict__ C,
    int M, int N, int K, int cmode, const int* __restrict__ flag) {
    const bool c32 = (cmode == 1) || (cmode == 2 && *flag != 0);
    const bool qkv = (cmode == 4);
    __shared__ __align__(16) u16 As[128 * 32];
    __shared__ __align__(16) u16 Bs[128 * 32];
    const int tid = threadIdx.x, lane = tid & 63, wave = tid >> 6;
    const int bm = blockIdx.y * 128, bn = blockIdx.x * 128;
    const int wm = (wave >> 1) * 64, wn = (wave & 1) * 64;
    const int fr = lane & 15, fq = lane >> 4;
    floatx4 acc[4][4] = {};

    const int srow = tid >> 2, scol = (tid & 3) * 8;       // 64 rows per call
    const long abase = (long)(bm + srow) * K + scol;
    const long bbase = (long)(bn + srow) * K + scol;
    char* lA = (char*)As + (tid & ~63) * 16;
    char* lB = (char*)Bs + (tid & ~63) * 16;

    for (int k0 = 0; k0 < K; k0 += 32) {
        __syncthreads();
        gload_lds16(A + abase + k0, lA);
        gload_lds16(A + abase + (long)64 * K + k0, lA + 4096);
        gload_lds16(B + bbase + k0, lB);
        gload_lds16(B + bbase + (long)64 * K + k0, lB + 4096);
        __syncthreads();
        bf16x8 af[4], bf[4];
#pragma unroll
        for (int i = 0; i < 4; i++) {
            af[i] = __builtin_bit_cast(bf16x8, *(const short8*)&As[(wm + i * 16 + fr) * 32 + fq * 8]);
            bf[i] = __builtin_bit_cast(bf16x8, *(const short8*)&Bs[(wn + i * 16 + fr) * 32 + fq * 8]);
        }
#pragma unroll
        for (int mi = 0; mi < 4; mi++)
#pragma unroll
            for (int ni = 0; ni < 4; ni++)
                acc[mi][ni] = __builtin_amdgcn_mfma_f32_16x16x32_bf16(
                    af[mi], bf[ni], acc[mi][ni], 0, 0, 0);
    }
#pragma unroll
    for (int mi = 0; mi < 4; mi++)
#pragma unroll
        for (int ni = 0; ni < 4; ni++)
#pragma unroll
            for (int r = 0; r < 4; r++) {
                const int m = bm + wm + mi * 16 + fq * 4 + r;
                const int n = bn + wn + ni * 16 + fr;
                const float val = acc[mi][ni][r];
                if (qkv) {
                    u16* base = (u16*)C;
                    long off;
                    if (n < 2048)      off = (long)m * 2048 + n;
                    else if (n < 4096) off = 8388608L + (long)m * 2048 + (n - 2048);
                    else               off = 16777216L + (long)m * 4096 + (n - 4096);
                    base[off] = f2b(val);
                } else {
                    const long ci = (long)m * N + n;
                    if (c32) ((float*)C)[ci] = val;
                    else ((u16*)C)[ci] = f2b(val);
                }
            }
}

// ---------------------------------------------------------------------------
// alpha/beta via MFMA: [4096,2048]x[32,2048]^T, sigmoid fused, transposed
// write to alphaT/betaT [b*16+h][T]. 64 blocks x (64m x 32n), BK=64.
// ---------------------------------------------------------------------------
__global__ __launch_bounds__(256) void ab_gemm(
    const u16* __restrict__ xb, const u16* __restrict__ wab,
    float* __restrict__ alphaT, float* __restrict__ betaT) {
    __shared__ __align__(16) u16 As[64 * 64];  // 8 KB
    __shared__ __align__(16) u16 Bs[32 * 64];  // 4 KB
    const int tid = threadIdx.x, lane = tid & 63, wave = tid >> 6;
    const int bm = blockIdx.x * 64;
    const int fr = lane & 15, fq = lane >> 4;
    floatx4 acc[2] = {};

    const int srow = tid >> 3, scol = (tid & 7) * 8;  // 32 rows x 64 cols per call
    char* lA = (char*)As + (tid & ~63) * 16;
    char* lB = (char*)Bs + (tid & ~63) * 16;

    for (int k0 = 0; k0 < 2048; k0 += 64) {
        __syncthreads();
        gload_lds16(xb + (long)(bm + srow) * 2048 + k0 + scol, lA);
        // rows 32..63 start at element 32*64=2048 -> byte offset 4096
        gload_lds16(xb + (long)(bm + 32 + srow) * 2048 + k0 + scol, lA + 4096);
        gload_lds16(wab + (long)srow * 2048 + k0 + scol, lB);
        __syncthreads();
#pragma unroll
        for (int ks = 0; ks < 2; ks++) {
            bf16x8 af = __builtin_bit_cast(bf16x8,
                *(const short8*)&As[(wave * 16 + fr) * 64 + ks * 32 + fq * 8]);
#pragma unroll
            for (int nt = 0; nt < 2; nt++) {
                bf16x8 bf = __builtin_bit_cast(bf16x8,
                    *(const short8*)&Bs[(nt * 16 + fr) * 64 + ks * 32 + fq * 8]);
                acc[nt] = __builtin_amdgcn_mfma_f32_16x16x32_bf16(af, bf, acc[nt], 0, 0, 0);
            }
        }
    }
#pragma unroll
    for (int nt = 0; nt < 2; nt++)
#pragma unroll
        for (int r = 0; r < 4; r++) {
            const int m = bm + wave * 16 + fq * 4 + r;
            const int n = nt * 16 + fr;
            const int b = m >> 11, t = m & 2047;
            const float s = 1.f / (1.f + __expf(-acc[nt][r]));
            if (n < 16) alphaT[((long)b * 16 + n) * 2048 + t] = s;
            else betaT[((long)b * 16 + (n - 16)) * 2048 + t] = s;
        }
}

// ---------------------------------------------------------------------------
// causal depthwise conv K=4 + SiLU + per-head(128) L2 norm. pre is bf16.
// ---------------------------------------------------------------------------
__global__ __launch_bounds__(256) void conv_silu_norm(
    const u16* __restrict__ pre, const void* __restrict__ cw,
    const void* __restrict__ cb, u16* __restrict__ out, const int* __restrict__ flag) {
    const bool f32 = (*flag != 0);
    const int bt = blockIdx.x;
    const int t = bt & 2047;
    const int tid = threadIdx.x;
    const int c0 = tid * 8;
    float y[8];
    float ss = 0.f;
#pragma unroll
    for (int j = 0; j < 8; j++) {
        const int c = c0 + j;
        float acc = ldf(cb, c, f32);
#pragma unroll
        for (int i = 0; i < 4; i++) {
            if (t - 3 + i >= 0)
                acc += ldf(cw, c * 4 + i, f32) * b2f(pre[(long)(bt - 3 + i) * 2048 + c]);
        }
        const float s = acc / (1.f + __expf(-acc));
        y[j] = s;
        ss += s * s;
    }
#pragma unroll
    for (int m = 1; m < 16; m <<= 1) ss += __shfl_xor(ss, m, 64);
    const float inv = rsqrtf(ss + 1e-12f);
#pragma unroll
    for (int j = 0; j < 8; j++) out[(long)bt * 2048 + c0 + j] = f2b(y[j] * inv);
}

__global__ __launch_bounds__(256) void conv_silu_v(
    const u16* __restrict__ pre, const void* __restrict__ cw,
    const void* __restrict__ cb, u16* __restrict__ out, const int* __restrict__ flag) {
    const bool f32 = (*flag != 0);
    const int bt = blockIdx.x;
    const int t = bt & 2047;
    const int tid = threadIdx.x;
    const int c0 = tid * 16;
#pragma unroll
    for (int j = 0; j < 16; j++) {
        const int c = c0 + j;
        float acc = ldf(cb, c, f32);
#pragma unroll
        for (int i = 0; i < 4; i++) {
            if (t - 3 + i >= 0)
                acc += ldf(cw, c * 4 + i, f32) * b2f(pre[(long)(bt - 3 + i) * 4096 + c]);
        }
        out[(long)bt * 4096 + c] = f2b(acc / (1.f + __expf(-acc)));
    }
}

// ---------------------------------------------------------------------------
// Gated delta-rule recurrence, barrier-free steps (DPP k-reduction).
// 256 blocks = (b,h,vb); lane = vq*8+kg owns S[kg*16+j][v]; red8 k-reduce.
// R12: REVERT of R11's dependency-break (measured regression: 468->562 µs,
// busy +87 cyc/step vs +28 predicted, idle unchanged -> idle is NOT the
// algebraic chain). Hot loop restored to the verified R10 form:
//  - 256 blocks, 1 wave/SIMD, S=16/lane (floatx2 x8), red8 k-reduce
//  - fully-unrolled tt loop, compile-time LDS offsets, no explicit pipeline
//  - packed float2 math (v_pk_fma_f32)
//  - f32 LDS staging + T14 async-STAGE split
// Fused QKV launcher (cmode 4) kept from R11 (measured ~-70 µs).
// ---------------------------------------------------------------------------
__global__ __launch_bounds__(256) void recurrence_kernel(
    const u16* __restrict__ qn, const u16* __restrict__ kn,
    const u16* __restrict__ vn, const float* __restrict__ alphaT,
    const float* __restrict__ betaT, const void* __restrict__ state_in,
    u16* __restrict__ outs, void* __restrict__ d_out, const int* __restrict__ flag) {
    const bool f32 = (*flag != 0);
    const int blk = blockIdx.x;
    const int vb = blk & 7, h = (blk >> 3) & 15, b = blk >> 7;
    const int tid = threadIdx.x, lane = tid & 63, wave = tid >> 6;
    const int kg = lane & 7, vq = lane >> 3;
    const int vloc = wave * 8 + vq;          // 0..31
    const int vglob = vb * 32 + vloc;

    // S2[p] = {S[2p], S[2p+1]}, state rows kg*16 + 2p, 2p+1
    floatx2 S2[8];
    const long stbase = ((long)(b * 16 + h) * 128 + kg * 16) * 256 + vglob;
#pragma unroll
    for (int p = 0; p < 8; p++) {
        S2[p][0] = ldf(state_in, stbase + (long)(2 * p) * 256, f32);
        S2[p][1] = ldf(state_in, stbase + (long)(2 * p + 1) * 256, f32);
    }

    // double-buffered f32 LDS (36 KB total)
    __shared__ __align__(16) float kf[2][16 * 128];
    __shared__ __align__(16) float qf[2][16 * 128];
    __shared__ __align__(16) float vf[2][16 * 32];

    // staging assignment: 16 rows x (16 threads x 8 cols) for k/q,
    // 16 rows x (16 threads x 2 cols) for v
    const int srow = tid >> 4, sc8 = (tid & 15) * 8, vc2 = (tid & 15) * 2;
    const long gkq0 = ((long)b * 2048 + srow) * 2048 + h * 128 + sc8;
    const long gv0  = ((long)b * 2048 + srow) * 4096 + h * 256 + vb * 32 + vc2;
    const long abase = (long)(b * 16 + h) * 2048;

    int4 gk, gq;
    unsigned int gv;
    float ga, gb;

    auto stage_write = [&](int buf) {
        const int kgg = sc8 >> 4, i0 = (sc8 >> 2) & 3;  // i0 in {0,2}
        float fk[8], fq_[8];
        unpack8(gk, fk);
        unpack8(gq, fq_);
        const int base = srow * 128 + kgg * 4;
        *(floatx4*)&kf[buf][base + i0 * 32]       = floatx4{fk[0], fk[1], fk[2], fk[3]};
        *(floatx4*)&kf[buf][base + (i0 + 1) * 32] = floatx4{fk[4], fk[5], fk[6], fk[7]};
        *(floatx4*)&qf[buf][base + i0 * 32]       = floatx4{fq_[0], fq_[1], fq_[2], fq_[3]};
        *(floatx4*)&qf[buf][base + (i0 + 1) * 32] = floatx4{fq_[4], fq_[5], fq_[6], fq_[7]};
        vf[buf][srow * 32 + vc2]     = b2f((u16)(gv & 0xffffu));
        vf[buf][srow * 32 + vc2 + 1] = b2f((u16)(gv >> 16));
    };

    // prologue: load + stage chunk 0
    gk = *(const int4*)(kn + gkq0);
    gq = *(const int4*)(qn + gkq0);
    gv = *(const unsigned int*)(vn + gv0);
    ga = alphaT[abase + (lane & 15)];
    gb = betaT[abase + (lane & 15)];
    stage_write(0);
    __syncthreads();

    for (int c = 0; c < 128; ++c) {
        const int cur = c & 1;
        const float aw = ga, bw = gb;  // capture current chunk's alpha/beta
        if (c + 1 < 128) {
            // T14: issue next chunk's global loads (consumed after compute)
            const long off = (long)(c + 1) * 16 * 2048;
            gk = *(const int4*)(kn + gkq0 + off);
            gq = *(const int4*)(qn + gkq0 + off);
            gv = *(const unsigned int*)(vn + gv0 + (long)(c + 1) * 16 * 4096);
            ga = alphaT[abase + (c + 1) * 16 + (lane & 15)];
            gb = betaT[abase + (c + 1) * 16 + (lane & 15)];
        }

        const float* kfp = kf[cur];
        const float* qfp = qf[cur];
        const float* vfp = vf[cur];
        const long obase = ((long)b * 2048 + c * 16) * 4096 + h * 256 + vglob;

#pragma unroll
        for (int tt = 0; tt < 16; ++tt) {
            // fragments: value kg*16 + i*4 + j at word tt*128 + i*32 + kg*4 + j
            floatx2 k2[8], q2[8];
#pragma unroll
            for (int i = 0; i < 4; i++) {
                const floatx4 k4 = *(const floatx4*)&kfp[tt * 128 + i * 32 + kg * 4];
                const floatx4 q4 = *(const floatx4*)&qfp[tt * 128 + i * 32 + kg * 4];
                k2[i * 2]     = __builtin_shufflevector(k4, k4, 0, 1);
                k2[i * 2 + 1] = __builtin_shufflevector(k4, k4, 2, 3);
                q2[i * 2]     = __builtin_shufflevector(q4, q4, 0, 1);
                q2[i * 2 + 1] = __builtin_shufflevector(q4, q4, 2, 3);
            }
            const float vcur = vfp[tt * 32 + vloc];
            const float a = __builtin_bit_cast(float,
                __builtin_amdgcn_readlane(__builtin_bit_cast(int, aw), tt));
            const float bb = __builtin_bit_cast(float,
                __builtin_amdgcn_readlane(__builtin_bit_cast(int, bw), tt));

            floatx2 accA = {0.f, 0.f}, accB = {0.f, 0.f};
#pragma unroll
            for (int p = 0; p < 4; p++) {
                accA = fma2(S2[p], k2[p], accA);
                accB = fma2(S2[4 + p], k2[4 + p], accB);
            }
            const floatx2 accR = accA + accB;
            const float r = red8(accR[0] + accR[1]);
            const float err = fmaf(-a, r, vcur);
            const float cc = bb * err;
            const floatx2 a2 = {a, a}, cc2 = {cc, cc};
            floatx2 oA = {0.f, 0.f}, oB = {0.f, 0.f};
#pragma unroll
            for (int p = 0; p < 4; p++) {
                S2[p] = fma2(cc2, k2[p], a2 * S2[p]);
                S2[4 + p] = fma2(cc2, k2[4 + p], a2 * S2[4 + p]);
                oA = fma2(S2[p], q2[p], oA);
                oB = fma2(S2[4 + p], q2[4 + p], oB);
            }
            const floatx2 accO = oA + oB;
            const float o = red8(accO[0] + accO[1]);
            if (kg == 0)
                outs[obase + (long)tt * 4096] = f2b(o);
        }

        if (c + 1 < 128) stage_write(cur ^ 1);  // compiler inserts vmcnt wait here
        __syncthreads();
    }

    // final state -> d_out at element offset B*T*H = 8388608
#pragma unroll
    for (int p = 0; p < 8; p++) {
#pragma unroll
        for (int e = 0; e < 2; e++) {
            const long idx = 8388608L + stbase + (long)(2 * p + e) * 256;
            if (f32) ((float*)d_out)[idx] = S2[p][e];
            else ((u16*)d_out)[idx] = f2b(S2[p][e]);
        }
    }
}

// ---------------------------------------------------------------------------
extern "C" void kernel_launch(void* const* d_in, const int* in_sizes, int n_in,
                              void* d_out, int out_size, void* d_ws, size_t ws_size,
                              hipStream_t stream) {
    const void* x   = d_in[0];
    const void* st0 = d_in[1];
    const void* Wq  = d_in[2];
    const void* Wk  = d_in[3];
    const void* Wv  = d_in[4];
    const void* Wo  = d_in[5];
    const void* Wa  = d_in[6];
    const void* Wb  = d_in[7];
    const void* qcW = d_in[8];
    const void* qcB = d_in[9];
    const void* kcW = d_in[10];
    const void* kcB = d_in[11];
    const void* vcW = d_in[12];
    const void* vcB = d_in[13];

    const int M = 4096;  // B*T
    const long MB = 1024L * 1024L;
    char* w = (char*)d_ws;
    int*   flag   = (int*)w;                       // @0, 1KB pad
    float* alphaT = (float*)(w + 1024);            // 256 KB
    float* betaT  = (float*)(w + 1024 + 262144);   // 256 KB
    u16*   wab    = (u16*)(w + 1024 + 524288);     // 128 KB (Wa||Wb bf16)
    u16* xb    = (u16*)(w + 1 * MB);               // 16 MB  (reused for Wo later)
    u16* wqb   = (u16*)(w + 17 * MB);              // 8 MB   (wqb/wkb/wvb contiguous:
    u16* wkb   = (u16*)(w + 25 * MB);              // 8 MB    fused [8192,2048] B)
    u16* wvb   = (u16*)(w + 33 * MB);              // 16 MB
    u16* qpreb = (u16*)(w + 49 * MB);              // 16 MB  (qpreb/kpreb/vpreb
    u16* kpreb = (u16*)(w + 65 * MB);              // 16 MB   contiguous: fused C)
    u16* vpreb = (u16*)(w + 81 * MB);              // 32 MB
    u16* qn    = (u16*)(w + 113 * MB);             // 16 MB
    u16* kn    = (u16*)(w + 129 * MB);             // 16 MB
    u16* vn    = (u16*)(w + 145 * MB);             // 32 MB (ends 177 MB)
    u16* wob   = xb;                               // alias: x dead after proj GEMMs + ab_gemm
    u16* outs  = qpreb;                            // alias: 32 MB (qpreb+kpreb)

    dim3 blk(256);
    detect_dtype<<<dim3(1), dim3(64), 0, stream>>>((const unsigned int*)x, flag);

    cvt_bf16<<<dim3(4096), blk, 0, stream>>>(x,  xb,  8388608L, flag);
    cvt_bf16<<<dim3(2048), blk, 0, stream>>>(Wq, wqb, 4194304L, flag);
    cvt_bf16<<<dim3(2048), blk, 0, stream>>>(Wk, wkb, 4194304L, flag);
    cvt_bf16<<<dim3(4096), blk, 0, stream>>>(Wv, wvb, 8388608L, flag);
    cvt_bf16<<<dim3(16),   blk, 0, stream>>>(Wa, wab, 32768L, flag);
    cvt_bf16<<<dim3(16),   blk, 0, stream>>>(Wb, wab + 32768, 32768L, flag);

    // fused QKV projection: one [4096,8192,2048] GEMM (cmode 4 splits C into
    // qpreb/kpreb/vpreb). Replaces 3 launches; 2048 blocks. (R11: ~-70 µs)
    gemm_bt128<<<dim3(8192 / 128, M / 128), blk, 0, stream>>>(xb, wqb, qpreb, M, 8192, 2048, 4, flag);
    ab_gemm<<<dim3(64), blk, 0, stream>>>(xb, wab, alphaT, betaT);

    cvt_bf16<<<dim3(4096), blk, 0, stream>>>(Wo, wob, 8388608L, flag);  // after all xb readers

    conv_silu_norm<<<dim3(M), blk, 0, stream>>>(qpreb, qcW, qcB, qn, flag);
    conv_silu_norm<<<dim3(M), blk, 0, stream>>>(kpreb, kcW, kcB, kn, flag);
    conv_silu_v<<<dim3(M), blk, 0, stream>>>(vpreb, vcW, vcB, vn, flag);

    recurrence_kernel<<<dim3(256), blk, 0, stream>>>(qn, kn, vn, alphaT, betaT, st0,
                                                     outs, d_out, flag);

    gemm_bt128<<<dim3(2048 / 128, M / 128), blk, 0, stream>>>(outs, wob, d_out, M, 2048, 4096, 2, flag);
}